// Round 11
// baseline (238.417 us; speedup 1.0000x reference)
//
#include <hip/hip_runtime.h>

#define LN_EPS 1e-5f

// ---------------------------------------------------------------------------
// MEASUREMENT ROUND 2 (r11): identical to r9 but kP x8 and kAttn x8.
//   P + A = (dur_us - 45.1) / 7.   (kG4LN known: 10.26 us warm, from r10.)
// Index algebra (verified passing rounds 2-10): unchanged.
//   F[which][b][g][cc][cs*64+d] = P_{which}[b, s_i, h_i*64+d] + bias
//   Dt[b][gq][gk][cc][cs] = dot64(Fq, Fk) / 8
//   SFK[b][c][d] = 32 * sum_gv FK[b][gv][c>>3][(c&7)*64+d]   (pre-scaled)
//   attn: per (q,k) softmax over 32 c of (vq&vk ? Dt : 0); masked -> 1/32.
//   A[c] = sum_k attn;  ctx[b,q,h*64+d] = sum_c A[c]*SFK[b][c][d].
//   attn_out == 1.0 everywhere.
// ---------------------------------------------------------------------------

#define FMA4(a, s, v) { (a).x += (s)*(v).x; (a).y += (s)*(v).y; \
                        (a).z += (s)*(v).z; (a).w += (s)*(v).w; }

__device__ __forceinline__ bool sniff_mask_bytes(const unsigned int* m) {
    unsigned int acc = 0;
#pragma unroll
    for (int i = 0; i < 16; ++i) acc |= m[i];
    return acc > 1u;
}

// kP: projections -> F.  64 blocks x 512 thr (8 waves share one W slice).
__global__ __launch_bounds__(512) void kP_proj(
    const float* __restrict__ Qin, const float* __restrict__ Kin,
    const float* __restrict__ WQ, const float* __restrict__ bQ,
    const float* __restrict__ WK, const float* __restrict__ bK,
    float* __restrict__ F)
{
    int bx = blockIdx.x;
    int h_i = bx & 7, b = (bx >> 3) & 1, which = bx >> 4;
    int g = h_i >> 1, cc2 = (h_i & 1) * 2;
    int t = threadIdx.x;

    const float* In   = which ? Kin : Qin;
    const float* W    = which ? WK  : WQ;
    const float* bias = which ? bK  : bQ;

    __shared__ float Xl[16][512];
    int sb0 = (h_i & 1) ? 0 : 240;
#pragma unroll
    for (int i = 0; i < 4; ++i) {
        int idx = (i * 512 + t);
        int rl = idx >> 7, m4 = idx & 127;
        int srow = sb0 + (rl >> 3) * 8 + (rl & 7);
        ((float4*)&Xl[rl][0])[m4] =
            ((const float4*)&In[(b * 256 + srow) * 512])[m4];
    }
    __syncthreads();

    int d = t & 63, rr = t >> 6;
    int n = h_i * 64 + d;
    float acc0 = 0.f, acc1 = 0.f;
    const float* wp = W + n;
#pragma unroll 8
    for (int m = 0; m < 512; ++m) {
        float w = wp[m * 512];
        acc0 += Xl[rr][m] * w;
        acc1 += Xl[rr + 8][m] * w;
    }
    float bb = bias[n];
    int base = ((which * 2 + b) * 4 + g) * 4;
    F[(base + cc2)     * 512 + rr * 64 + d] = acc0 + bb;
    F[(base + cc2 + 1) * 512 + rr * 64 + d] = acc1 + bb;
}

// kC: Dt (8-lane dots + shfl) and SFK (pre-scaled x32).  48 blocks x 256 thr.
__global__ void kC_dtab_sfk(const float* __restrict__ F, float* __restrict__ Dt,
                            float* __restrict__ SFK) {
    int slot = blockIdx.x * 256 + threadIdx.x;
    if (slot < 8192) {
        int part = slot & 7, e = slot >> 3;
        int cs = e & 7, cc = (e >> 3) & 3, gk = (e >> 5) & 3,
            gq = (e >> 7) & 3, b = (e >> 9) & 1;
        const float* fq = F + ((b * 4 + gq) * 4 + cc) * 512 + cs * 64 + part * 8;
        const float* fk = F + (((2 + b) * 4 + gk) * 4 + cc) * 512 + cs * 64 + part * 8;
        float a = 0.f;
#pragma unroll
        for (int u = 0; u < 8; ++u) a += fq[u] * fk[u];
        a += __shfl_xor(a, 1);
        a += __shfl_xor(a, 2);
        a += __shfl_xor(a, 4);
        if (part == 0) Dt[e] = a * 0.125f;
    } else {
        int e = slot - 8192;
        int d = e & 63, c = (e >> 6) & 31, b = e >> 11;
        float a = 0.f;
#pragma unroll
        for (int gv = 0; gv < 4; ++gv)
            a += F[(((2 + b) * 4 + gv) * 4 + (c >> 3)) * 512 + (c & 7) * 64 + d];
        SFK[e] = 32.f * a;
    }
}

// kAttn: 1024 blocks x 256 thr.  Wave per (h,q); 2 lanes per k, 16 c each.
__global__ void kAttn(const float* __restrict__ Dt, const void* __restrict__ maskp,
                      const float* __restrict__ SFK, float* __restrict__ ctx,
                      float* __restrict__ attnp, int fill) {
    __shared__ float aws[4][32];
    int vb = blockIdx.x, t = threadIdx.x;
    if (fill) ((float4*)attnp)[vb * 256 + t] = make_float4(1.f, 1.f, 1.f, 1.f);
    int qb = vb & 63, h = (vb >> 6) & 7, b = vb >> 9;
    int wave = t >> 6, l = t & 63;
    int q = qb * 4 + wave;
    int half = l & 1, klo = l >> 1;
    int g_q = q & 3;
    int i_q = h * 32 + (q >> 3);
    bool up_q = (q & 4) == 0;
    int ak = klo & 3;
    bool up_k = (klo & 4) == 0;

    bool mbytes = sniff_mask_bytes((const unsigned int*)maskp);

    float sq[16];
    const float* Db = Dt + ((b * 4 + g_q) * 4 + ak) * 32 + half * 16;
#pragma unroll
    for (int j = 0; j < 16; ++j) {
        int cc = half * 2 + (j >> 3);
        int row = g_q * 64 + 30 + cc;
        bool vq = up_q ? (i_q >= 256 - row) : (i_q <= 255 - row);
        sq[j] = vq ? Db[j] : 0.f;
    }

    float A[16];
#pragma unroll
    for (int j = 0; j < 16; ++j) A[j] = 0.f;

    int qrow = (b * 256 + q) * 256;
    for (int r = 0; r < 8; ++r) {
        int k = r * 32 + klo;
        bool masked = mbytes ? (((const unsigned char*)maskp)[qrow + k] != 0)
                             : (((const int*)maskp)[qrow + k] != 0);
        if (masked) {
#pragma unroll
            for (int j = 0; j < 16; ++j) A[j] += 0.03125f;
            continue;
        }
        int i_k = h * 32 + (k >> 3);
        float s[16];
        float mx = -1e30f;
#pragma unroll
        for (int j = 0; j < 16; ++j) {
            int cc = half * 2 + (j >> 3);
            int row = ak * 64 + 30 + cc;
            bool vk = up_k ? (i_k >= 256 - row) : (i_k <= 255 - row);
            s[j] = vk ? sq[j] : 0.f;
            mx = fmaxf(mx, s[j]);
        }
        mx = fmaxf(mx, __shfl_xor(mx, 1));
        float den = 0.f;
#pragma unroll
        for (int j = 0; j < 16; ++j) { s[j] = __expf(s[j] - mx); den += s[j]; }
        den += __shfl_xor(den, 1);
        float inv = 1.f / den;
#pragma unroll
        for (int j = 0; j < 16; ++j) A[j] += s[j] * inv;
    }

#pragma unroll
    for (int off = 2; off < 64; off <<= 1) {
#pragma unroll
        for (int j = 0; j < 16; ++j) A[j] += __shfl_xor(A[j], off);
    }

    float* aw = aws[wave];
    if (l < 2) {
#pragma unroll
        for (int j = 0; j < 16; ++j) aw[l * 16 + j] = A[j];
    }
    float acc = 0.f;
    const float* S = SFK + b * 2048;
#pragma unroll
    for (int c = 0; c < 32; ++c) acc += aw[c] * S[c * 64 + l];
    ctx[(b * 256 + q) * 512 + h * 64 + l] = acc;
}

// kG4LN: outer-product Wo GEMM + bias + residual + LayerNorm, fused.
// 128 blocks x 512 thr; block = 4 output rows.  (r9 version, unchanged.)
__global__ __launch_bounds__(512) void kG4LN(
    const float* __restrict__ ctx, const float* __restrict__ Wo,
    const float* __restrict__ bo, const float* __restrict__ Qin,
    const float* __restrict__ gamma, const float* __restrict__ beta,
    float* __restrict__ out)
{
    __shared__ float  Cl[4][512];
    __shared__ float4 red4[8][4][64];
    __shared__ float  red2[8][2];

    int t = threadIdx.x, r0 = blockIdx.x * 4;
    int w = t >> 6, l = t & 63;

    ((float4*)Cl)[t] = ((const float4*)&ctx[r0 * 512])[t];
    __syncthreads();

    const float4* WoV = (const float4*)Wo;
    const float4* pA = WoV + (size_t)(w * 64) * 128 + l;
    const float4* pB = pA + 64;
    float4 a0A = {0,0,0,0}, a1A = {0,0,0,0}, a2A = {0,0,0,0}, a3A = {0,0,0,0};
    float4 a0B = {0,0,0,0}, a1B = {0,0,0,0}, a2B = {0,0,0,0}, a3B = {0,0,0,0};
    int m0 = w * 64;
    float4 wA = pA[0], wB = pB[0];
#pragma unroll 4
    for (int mm = 0; mm < 63; ++mm) {
        float4 nA = pA[(mm + 1) * 128];
        float4 nB = pB[(mm + 1) * 128];
        float s0 = Cl[0][m0 + mm], s1 = Cl[1][m0 + mm];
        float s2 = Cl[2][m0 + mm], s3 = Cl[3][m0 + mm];
        FMA4(a0A, s0, wA); FMA4(a1A, s1, wA); FMA4(a2A, s2, wA); FMA4(a3A, s3, wA);
        FMA4(a0B, s0, wB); FMA4(a1B, s1, wB); FMA4(a2B, s2, wB); FMA4(a3B, s3, wB);
        wA = nA; wB = nB;
    }
    {
        float s0 = Cl[0][m0 + 63], s1 = Cl[1][m0 + 63];
        float s2 = Cl[2][m0 + 63], s3 = Cl[3][m0 + 63];
        FMA4(a0A, s0, wA); FMA4(a1A, s1, wA); FMA4(a2A, s2, wA); FMA4(a3A, s3, wA);
        FMA4(a0B, s0, wB); FMA4(a1B, s1, wB); FMA4(a2B, s2, wB); FMA4(a3B, s3, wB);
    }

    red4[w][0][l] = a0A; red4[w][1][l] = a1A; red4[w][2][l] = a2A; red4[w][3][l] = a3A;
    __syncthreads();
    if (t < 256) {
        int r = t >> 6, c4 = t & 63;
        float4 s = red4[0][r][c4];
#pragma unroll
        for (int w2 = 1; w2 < 8; ++w2) {
            float4 v = red4[w2][r][c4];
            s.x += v.x; s.y += v.y; s.z += v.z; s.w += v.w;
        }
        float4 bb = ((const float4*)bo)[c4];
        float4 qq = ((const float4*)Qin)[(r0 + r) * 128 + c4];
        s.x += bb.x + qq.x; s.y += bb.y + qq.y;
        s.z += bb.z + qq.z; s.w += bb.w + qq.w;
        *(float4*)&Cl[r][c4 * 4] = s;
    }
    __syncthreads();
    red4[w][0][l] = a0B; red4[w][1][l] = a1B; red4[w][2][l] = a2B; red4[w][3][l] = a3B;
    __syncthreads();
    if (t < 256) {
        int r = t >> 6, c4 = t & 63;
        float4 s = red4[0][r][c4];
#pragma unroll
        for (int w2 = 1; w2 < 8; ++w2) {
            float4 v = red4[w2][r][c4];
            s.x += v.x; s.y += v.y; s.z += v.z; s.w += v.w;
        }
        float4 bb = ((const float4*)bo)[64 + c4];
        float4 qq = ((const float4*)Qin)[(r0 + r) * 128 + 64 + c4];
        s.x += bb.x + qq.x; s.y += bb.y + qq.y;
        s.z += bb.z + qq.z; s.w += bb.w + qq.w;
        *(float4*)&Cl[r][256 + c4 * 4] = s;
    }
    __syncthreads();

    int r = t >> 7, c = t & 127;
    float v0 = Cl[r][c], v1 = Cl[r][c + 128], v2 = Cl[r][c + 256], v3 = Cl[r][c + 384];
    float s1 = v0 + v1 + v2 + v3;
    float s2 = v0 * v0 + v1 * v1 + v2 * v2 + v3 * v3;
#pragma unroll
    for (int off = 1; off < 64; off <<= 1) {
        s1 += __shfl_xor(s1, off);
        s2 += __shfl_xor(s2, off);
    }
    if (l == 0) { red2[w][0] = s1; red2[w][1] = s2; }
    __syncthreads();
    float tot1 = red2[2 * r][0] + red2[2 * r + 1][0];
    float tot2 = red2[2 * r][1] + red2[2 * r + 1][1];
    float mu = tot1 * (1.f / 512.f);
    float var = tot2 * (1.f / 512.f) - mu * mu;
    float rs = rsqrtf(var + LN_EPS);
    float* op = out + (r0 + r) * 512;
    op[c]       = (v0 - mu) * rs * gamma[c]       + beta[c];
    op[c + 128] = (v1 - mu) * rs * gamma[c + 128] + beta[c + 128];
    op[c + 256] = (v2 - mu) * rs * gamma[c + 256] + beta[c + 256];
    op[c + 384] = (v3 - mu) * rs * gamma[c + 384] + beta[c + 384];
}

// plan-B only: restore attn_out region (which hosted scratch) to 1.0
__global__ void k5_fill(float* __restrict__ p, int n) {
    int i = (blockIdx.x * 256 + threadIdx.x) * 4;
    float4 one = make_float4(1.f, 1.f, 1.f, 1.f);
    for (; i < n; i += gridDim.x * 256 * 4) *(float4*)(p + i) = one;
}

extern "C" void kernel_launch(void* const* d_in, const int* in_sizes, int n_in,
                              void* d_out, int out_size, void* d_ws, size_t ws_size,
                              hipStream_t stream) {
    (void)in_sizes; (void)n_in; (void)out_size;
    const float* Qin  = (const float*)d_in[0];
    const float* Kin  = (const float*)d_in[1];
    const void*  mask = d_in[3];
    const float* WQ   = (const float*)d_in[4];
    const float* bQ   = (const float*)d_in[5];
    const float* WK   = (const float*)d_in[6];
    const float* bK   = (const float*)d_in[7];
    const float* Wo   = (const float*)d_in[10];
    const float* bo   = (const float*)d_in[11];
    const float* gamma= (const float*)d_in[12];
    const float* beta = (const float*)d_in[13];

    float* out   = (float*)d_out;
    float* attnp = out + 262144;                  // 1,048,576 floats (output 1)

    const size_t NEED = 300032ull * sizeof(float);
    int fill;
    float* scr;
    if (ws_size >= NEED) { scr = (float*)d_ws; fill = 1; }   // plan A
    else                 { scr = attnp;        fill = 0; }   // plan B

    float* F   = scr;                             // 32768
    float* Dt  = scr + 32768;                     // 1024
    float* SFK = scr + 33792;                     // 4096 (pre-scaled x32)
    float* ctx = scr + 37888;                     // 262144

    // MEASUREMENT: kP x8 and kAttn x8 (both idempotent).
    // P + A = (dur - 45.1) / 7.
    for (int rep = 0; rep < 8; ++rep) {
        kP_proj<<<dim3(64),   dim3(512), 0, stream>>>(Qin, Kin, WQ, bQ, WK, bK, F);
    }
    kC_dtab_sfk<<<dim3(48),  dim3(256), 0, stream>>>(F, Dt, SFK);
    for (int rep = 0; rep < 8; ++rep) {
        kAttn  <<<dim3(1024), dim3(256), 0, stream>>>(Dt, mask, SFK, ctx, attnp, fill);
    }
    kG4LN      <<<dim3(128), dim3(512), 0, stream>>>(ctx, Wo, bo, Qin, gamma, beta, out);
    if (!fill) k5_fill<<<dim3(256), dim3(256), 0, stream>>>(attnp, 1048576);
}

// Round 12
// 39.943 us; speedup vs baseline: 5.9689x; 5.9689x over previous
//
#include <hip/hip_runtime.h>

#define LN_EPS 1e-5f

// ---------------------------------------------------------------------------
// Index algebra (verified passing rounds 2-11):
//   F[which][b][g][cc][cs*64+d] = P_{which}[b, s_i, h_i*64+d] + bias
//     s_i = (cc<2 ? 240+8*cc : 8*(cc-2)) + cs,  h_i = g*2 + (cc>>1)
//   Dt[b][gq][gk][cc][cs] = dot64(Fq, Fk) / 8
//   SFK[b][c][d] = 32 * sum_gv FK[b][gv][c>>3][(c&7)*64+d]   (pre-scaled)
//   attn: per (q,k) softmax over 32 c of (vq&vk ? Dt : 0); masked -> 1/32.
//   A[c] = sum_k attn;  ctx[b,q,h*64+d] = sum_c A[c]*SFK[b][c][d].
//   attn_out == 1.0 everywhere.
// MEASURED LEDGER (r10/r11 repeat-measurements, warm):
//   kP(512-deep col-walk, L1-shared)  ~21 us   <- the pig; replaced by kA+kB
//   kA+kB(64-deep split-K, 512 blks)  ~5 us    (r3 structure, measured fast)
//   kAttn ~5 us | kG4LN ~10.3 us | kC ~1 us | overhead ~8 us
// PERF LAW (final form): column-strided walks cost ~depth x ~40-100cy even
// L1-hot; survivable only at depth<=64 with >=4096 waves of TLP.
// ---------------------------------------------------------------------------

#define FMA4(a, s, v) { (a).x += (s)*(v).x; (a).y += (s)*(v).y; \
                        (a).z += (s)*(v).z; (a).w += (s)*(v).w; }

__device__ __forceinline__ bool sniff_mask_bytes(const unsigned int* m) {
    unsigned int acc = 0;
#pragma unroll
    for (int i = 0; i < 16; ++i) acc |= m[i];
    return acc > 1u;
}

// kA: projection GEMM, split-K (K-chunk 64).  512 blocks x 512 thr.
__global__ __launch_bounds__(512) void kA_proj_part(
    const float* __restrict__ Qin, const float* __restrict__ Kin,
    const float* __restrict__ WQ, const float* __restrict__ WK,
    float* __restrict__ Ppart)
{
    int bx = blockIdx.x;
    int cc = bx & 3, g = (bx >> 2) & 3, b = (bx >> 4) & 1, which = (bx >> 5) & 1, kc = bx >> 6;
    int t = threadIdx.x, d = t & 63, cs = t >> 6;

    const float* In = which ? Kin : Qin;
    const float* W  = which ? WK  : WQ;
    int sbase = (cc < 2) ? (240 + 8 * cc) : (8 * (cc - 2));
    int n = (g * 2 + (cc >> 1)) * 64 + d;

    const float* xrow = In + (b * 256 + sbase + cs) * 512 + kc * 64;
    const float* wcol = W + (kc * 64) * 512 + n;
    float acc = 0.f;
#pragma unroll 8
    for (int m = 0; m < 64; ++m) acc += xrow[m] * wcol[m * 512];

    int fsub = (((which * 2 + b) * 4 + g) * 4 + cc) * 512 + cs * 64 + d;
    Ppart[kc * 32768 + fsub] = acc;
}

// kB: F[f] = sum_kc Ppart[kc][f] + bias.  128 blocks x 256 thr.
__global__ void kB_proj_red(const float* __restrict__ Ppart,
                            const float* __restrict__ bQ, const float* __restrict__ bK,
                            float* __restrict__ F) {
    int f = blockIdx.x * 256 + threadIdx.x;
    float acc = 0.f;
#pragma unroll
    for (int kc = 0; kc < 8; ++kc) acc += Ppart[kc * 32768 + f];
    int which = f >> 14, cc = (f >> 9) & 3, g = (f >> 11) & 3, d = f & 63;
    int n = (g * 2 + (cc >> 1)) * 64 + d;
    F[f] = acc + (which ? bK[n] : bQ[n]);
}

// kC: Dt (8-lane dots + shfl) and SFK (pre-scaled x32).  48 blocks x 256 thr.
__global__ void kC_dtab_sfk(const float* __restrict__ F, float* __restrict__ Dt,
                            float* __restrict__ SFK) {
    int slot = blockIdx.x * 256 + threadIdx.x;
    if (slot < 8192) {
        int part = slot & 7, e = slot >> 3;
        int cs = e & 7, cc = (e >> 3) & 3, gk = (e >> 5) & 3,
            gq = (e >> 7) & 3, b = (e >> 9) & 1;
        const float* fq = F + ((b * 4 + gq) * 4 + cc) * 512 + cs * 64 + part * 8;
        const float* fk = F + (((2 + b) * 4 + gk) * 4 + cc) * 512 + cs * 64 + part * 8;
        float a = 0.f;
#pragma unroll
        for (int u = 0; u < 8; ++u) a += fq[u] * fk[u];
        a += __shfl_xor(a, 1);
        a += __shfl_xor(a, 2);
        a += __shfl_xor(a, 4);
        if (part == 0) Dt[e] = a * 0.125f;
    } else {
        int e = slot - 8192;
        int d = e & 63, c = (e >> 6) & 31, b = e >> 11;
        float a = 0.f;
#pragma unroll
        for (int gv = 0; gv < 4; ++gv)
            a += F[(((2 + b) * 4 + gv) * 4 + (c >> 3)) * 512 + (c & 7) * 64 + d];
        SFK[e] = 32.f * a;
    }
}

// kAttn: 1024 blocks x 256 thr.  Wave per (h,q); 2 lanes per k, 16 c each.
__global__ void kAttn(const float* __restrict__ Dt, const void* __restrict__ maskp,
                      const float* __restrict__ SFK, float* __restrict__ ctx,
                      float* __restrict__ attnp, int fill) {
    __shared__ float aws[4][32];
    int vb = blockIdx.x, t = threadIdx.x;
    if (fill) ((float4*)attnp)[vb * 256 + t] = make_float4(1.f, 1.f, 1.f, 1.f);
    int qb = vb & 63, h = (vb >> 6) & 7, b = vb >> 9;
    int wave = t >> 6, l = t & 63;
    int q = qb * 4 + wave;
    int half = l & 1, klo = l >> 1;
    int g_q = q & 3;
    int i_q = h * 32 + (q >> 3);
    bool up_q = (q & 4) == 0;
    int ak = klo & 3;
    bool up_k = (klo & 4) == 0;

    bool mbytes = sniff_mask_bytes((const unsigned int*)maskp);

    float sq[16];
    const float* Db = Dt + ((b * 4 + g_q) * 4 + ak) * 32 + half * 16;
#pragma unroll
    for (int j = 0; j < 16; ++j) {
        int cc = half * 2 + (j >> 3);
        int row = g_q * 64 + 30 + cc;
        bool vq = up_q ? (i_q >= 256 - row) : (i_q <= 255 - row);
        sq[j] = vq ? Db[j] : 0.f;
    }

    float A[16];
#pragma unroll
    for (int j = 0; j < 16; ++j) A[j] = 0.f;

    int qrow = (b * 256 + q) * 256;
    for (int r = 0; r < 8; ++r) {
        int k = r * 32 + klo;
        bool masked = mbytes ? (((const unsigned char*)maskp)[qrow + k] != 0)
                             : (((const int*)maskp)[qrow + k] != 0);
        if (masked) {
#pragma unroll
            for (int j = 0; j < 16; ++j) A[j] += 0.03125f;
            continue;
        }
        int i_k = h * 32 + (k >> 3);
        float s[16];
        float mx = -1e30f;
#pragma unroll
        for (int j = 0; j < 16; ++j) {
            int cc = half * 2 + (j >> 3);
            int row = ak * 64 + 30 + cc;
            bool vk = up_k ? (i_k >= 256 - row) : (i_k <= 255 - row);
            s[j] = vk ? sq[j] : 0.f;
            mx = fmaxf(mx, s[j]);
        }
        mx = fmaxf(mx, __shfl_xor(mx, 1));
        float den = 0.f;
#pragma unroll
        for (int j = 0; j < 16; ++j) { s[j] = __expf(s[j] - mx); den += s[j]; }
        den += __shfl_xor(den, 1);
        float inv = 1.f / den;
#pragma unroll
        for (int j = 0; j < 16; ++j) A[j] += s[j] * inv;
    }

#pragma unroll
    for (int off = 2; off < 64; off <<= 1) {
#pragma unroll
        for (int j = 0; j < 16; ++j) A[j] += __shfl_xor(A[j], off);
    }

    float* aw = aws[wave];
    if (l < 2) {
#pragma unroll
        for (int j = 0; j < 16; ++j) aw[l * 16 + j] = A[j];
    }
    float acc = 0.f;
    const float* S = SFK + b * 2048;
#pragma unroll
    for (int c = 0; c < 32; ++c) acc += aw[c] * S[c * 64 + l];
    ctx[(b * 256 + q) * 512 + h * 64 + l] = acc;
}

// kG4LN: outer-product Wo GEMM + bias + residual + LayerNorm, fused.
// 128 blocks x 512 thr; block = 4 output rows.  (r9 version, ~10.3us warm.)
__global__ __launch_bounds__(512) void kG4LN(
    const float* __restrict__ ctx, const float* __restrict__ Wo,
    const float* __restrict__ bo, const float* __restrict__ Qin,
    const float* __restrict__ gamma, const float* __restrict__ beta,
    float* __restrict__ out)
{
    __shared__ float  Cl[4][512];
    __shared__ float4 red4[8][4][64];
    __shared__ float  red2[8][2];

    int t = threadIdx.x, r0 = blockIdx.x * 4;
    int w = t >> 6, l = t & 63;

    ((float4*)Cl)[t] = ((const float4*)&ctx[r0 * 512])[t];
    __syncthreads();

    const float4* WoV = (const float4*)Wo;
    const float4* pA = WoV + (size_t)(w * 64) * 128 + l;
    const float4* pB = pA + 64;
    float4 a0A = {0,0,0,0}, a1A = {0,0,0,0}, a2A = {0,0,0,0}, a3A = {0,0,0,0};
    float4 a0B = {0,0,0,0}, a1B = {0,0,0,0}, a2B = {0,0,0,0}, a3B = {0,0,0,0};
    int m0 = w * 64;
    float4 wA = pA[0], wB = pB[0];
#pragma unroll 4
    for (int mm = 0; mm < 63; ++mm) {
        float4 nA = pA[(mm + 1) * 128];
        float4 nB = pB[(mm + 1) * 128];
        float s0 = Cl[0][m0 + mm], s1 = Cl[1][m0 + mm];
        float s2 = Cl[2][m0 + mm], s3 = Cl[3][m0 + mm];
        FMA4(a0A, s0, wA); FMA4(a1A, s1, wA); FMA4(a2A, s2, wA); FMA4(a3A, s3, wA);
        FMA4(a0B, s0, wB); FMA4(a1B, s1, wB); FMA4(a2B, s2, wB); FMA4(a3B, s3, wB);
        wA = nA; wB = nB;
    }
    {
        float s0 = Cl[0][m0 + 63], s1 = Cl[1][m0 + 63];
        float s2 = Cl[2][m0 + 63], s3 = Cl[3][m0 + 63];
        FMA4(a0A, s0, wA); FMA4(a1A, s1, wA); FMA4(a2A, s2, wA); FMA4(a3A, s3, wA);
        FMA4(a0B, s0, wB); FMA4(a1B, s1, wB); FMA4(a2B, s2, wB); FMA4(a3B, s3, wB);
    }

    red4[w][0][l] = a0A; red4[w][1][l] = a1A; red4[w][2][l] = a2A; red4[w][3][l] = a3A;
    __syncthreads();
    if (t < 256) {
        int r = t >> 6, c4 = t & 63;
        float4 s = red4[0][r][c4];
#pragma unroll
        for (int w2 = 1; w2 < 8; ++w2) {
            float4 v = red4[w2][r][c4];
            s.x += v.x; s.y += v.y; s.z += v.z; s.w += v.w;
        }
        float4 bb = ((const float4*)bo)[c4];
        float4 qq = ((const float4*)Qin)[(r0 + r) * 128 + c4];
        s.x += bb.x + qq.x; s.y += bb.y + qq.y;
        s.z += bb.z + qq.z; s.w += bb.w + qq.w;
        *(float4*)&Cl[r][c4 * 4] = s;
    }
    __syncthreads();
    red4[w][0][l] = a0B; red4[w][1][l] = a1B; red4[w][2][l] = a2B; red4[w][3][l] = a3B;
    __syncthreads();
    if (t < 256) {
        int r = t >> 6, c4 = t & 63;
        float4 s = red4[0][r][c4];
#pragma unroll
        for (int w2 = 1; w2 < 8; ++w2) {
            float4 v = red4[w2][r][c4];
            s.x += v.x; s.y += v.y; s.z += v.z; s.w += v.w;
        }
        float4 bb = ((const float4*)bo)[64 + c4];
        float4 qq = ((const float4*)Qin)[(r0 + r) * 128 + 64 + c4];
        s.x += bb.x + qq.x; s.y += bb.y + qq.y;
        s.z += bb.z + qq.z; s.w += bb.w + qq.w;
        *(float4*)&Cl[r][256 + c4 * 4] = s;
    }
    __syncthreads();

    int r = t >> 7, c = t & 127;
    float v0 = Cl[r][c], v1 = Cl[r][c + 128], v2 = Cl[r][c + 256], v3 = Cl[r][c + 384];
    float s1 = v0 + v1 + v2 + v3;
    float s2 = v0 * v0 + v1 * v1 + v2 * v2 + v3 * v3;
#pragma unroll
    for (int off = 1; off < 64; off <<= 1) {
        s1 += __shfl_xor(s1, off);
        s2 += __shfl_xor(s2, off);
    }
    if (l == 0) { red2[w][0] = s1; red2[w][1] = s2; }
    __syncthreads();
    float tot1 = red2[2 * r][0] + red2[2 * r + 1][0];
    float tot2 = red2[2 * r][1] + red2[2 * r + 1][1];
    float mu = tot1 * (1.f / 512.f);
    float var = tot2 * (1.f / 512.f) - mu * mu;
    float rs = rsqrtf(var + LN_EPS);
    float* op = out + (r0 + r) * 512;
    op[c]       = (v0 - mu) * rs * gamma[c]       + beta[c];
    op[c + 128] = (v1 - mu) * rs * gamma[c + 128] + beta[c + 128];
    op[c + 256] = (v2 - mu) * rs * gamma[c + 256] + beta[c + 256];
    op[c + 384] = (v3 - mu) * rs * gamma[c + 384] + beta[c + 384];
}

// plan-B only: restore attn_out region (which hosted scratch) to 1.0
__global__ void k5_fill(float* __restrict__ p, int n) {
    int i = (blockIdx.x * 256 + threadIdx.x) * 4;
    float4 one = make_float4(1.f, 1.f, 1.f, 1.f);
    for (; i < n; i += gridDim.x * 256 * 4) *(float4*)(p + i) = one;
}

extern "C" void kernel_launch(void* const* d_in, const int* in_sizes, int n_in,
                              void* d_out, int out_size, void* d_ws, size_t ws_size,
                              hipStream_t stream) {
    (void)in_sizes; (void)n_in; (void)out_size;
    const float* Qin  = (const float*)d_in[0];
    const float* Kin  = (const float*)d_in[1];
    const void*  mask = d_in[3];
    const float* WQ   = (const float*)d_in[4];
    const float* bQ   = (const float*)d_in[5];
    const float* WK   = (const float*)d_in[6];
    const float* bK   = (const float*)d_in[7];
    const float* Wo   = (const float*)d_in[10];
    const float* bo   = (const float*)d_in[11];
    const float* gamma= (const float*)d_in[12];
    const float* beta = (const float*)d_in[13];

    float* out   = (float*)d_out;
    float* attnp = out + 262144;                  // 1,048,576 floats (output 1)

    const size_t NEED = 562176ull * sizeof(float);
    if (ws_size >= NEED) {
        // Plan A: scratch in d_ws.
        float* ws    = (float*)d_ws;
        float* Ppart = ws;                        // 262144
        float* F     = ws + 262144;               // 32768
        float* Dt    = ws + 294912;               // 1024
        float* SFK   = ws + 295936;               // 4096
        float* ctx   = ws + 300032;               // 262144

        kA_proj_part<<<dim3(512),  dim3(512), 0, stream>>>(Qin, Kin, WQ, WK, Ppart);
        kB_proj_red <<<dim3(128),  dim3(256), 0, stream>>>(Ppart, bQ, bK, F);
        kC_dtab_sfk <<<dim3(48),   dim3(256), 0, stream>>>(F, Dt, SFK);
        kAttn       <<<dim3(1024), dim3(256), 0, stream>>>(Dt, mask, SFK, ctx, attnp, 1);
        kG4LN       <<<dim3(128),  dim3(512), 0, stream>>>(ctx, Wo, bo, Qin, gamma, beta, out);
    } else {
        // Plan B: scratch in attn_out region; restore with fill at end.
        float* Ppart = attnp;                     // [0, 262144)
        float* F     = attnp + 262144;            // [262144, 294912)
        float* Dt    = attnp + 294912;            // [294912, 295936)
        float* SFK   = attnp + 295936;            // [295936, 300032)
        float* ctx   = attnp + 786432;            // [786432, 1048576)

        kA_proj_part<<<dim3(512),  dim3(512), 0, stream>>>(Qin, Kin, WQ, WK, Ppart);
        kB_proj_red <<<dim3(128),  dim3(256), 0, stream>>>(Ppart, bQ, bK, F);
        kC_dtab_sfk <<<dim3(48),   dim3(256), 0, stream>>>(F, Dt, SFK);
        kAttn       <<<dim3(1024), dim3(256), 0, stream>>>(Dt, mask, SFK, ctx, attnp, 0);
        kG4LN       <<<dim3(128),  dim3(512), 0, stream>>>(ctx, Wo, bo, Qin, gamma, beta, out);
        k5_fill     <<<dim3(256),  dim3(256), 0, stream>>>(attnp, 1048576);
    }
}

// Round 13
// 38.705 us; speedup vs baseline: 6.1599x; 1.0320x over previous
//
#include <hip/hip_runtime.h>

#define LN_EPS 1e-5f

// ---------------------------------------------------------------------------
// Index algebra (verified passing rounds 2-12):
//   F[which][b][g][cc][cs*64+d] = P_{which}[b, s_i, h_i*64+d] + bias
//     s_i = (cc<2 ? 240+8*cc : 8*(cc-2)) + cs,  h_i = g*2 + (cc>>1)
//   Dt[b][gq][gk][cc][cs] = dot64(Fq, Fk) / 8
//   SFK[b][c][d] = 32 * sum_gv FK[b][gv][c>>3][(c&7)*64+d]   (pre-scaled)
//   attn: per (q,k) softmax over 32 c of (vq&vk ? Dt : 0); masked -> 1/32.
//   A[c] = sum_k attn;  ctx[b,q,h*64+d] = sum_c A[c]*SFK[b][c][d].
//   attn_out == 1.0 everywhere.
// MEASURED LEDGER (r10-r12, warm):
//   kG4LN+gap = 10.26 | kP+kAttn+2gap = 27.6 | kA+kB ~11 (col-walk tax)
//   kAttn ~6.5 | kC ~1 | fixed+gaps ~10
// PERF LAW: column-strided walks (even 256B wave-segments, L1-hot) cost
// ~84cy/step regardless of occupancy. Only row-major float4 streaming with
// LDS-broadcast scalars (outer product) avoids the tax -> kAo below.
// ---------------------------------------------------------------------------

#define FMA4(a, s, v) { (a).x += (s)*(v).x; (a).y += (s)*(v).y; \
                        (a).z += (s)*(v).z; (a).w += (s)*(v).w; }

__device__ __forceinline__ bool sniff_mask_bytes(const unsigned int* m) {
    unsigned int acc = 0;
#pragma unroll
    for (int i = 0; i < 16; ++i) acc |= m[i];
    return acc > 1u;
}

// kAo: projection, outer-product split-K.  64 blocks = which(2) x b(2) x mc(16);
// 512 thr = one output column n each.  Per m: one coalesced 2KB W-row load +
// 16 FMAs vs LDS-broadcast X.  NO column walks.
__global__ __launch_bounds__(512) void kAo_proj_part(
    const float* __restrict__ Qin, const float* __restrict__ Kin,
    const float* __restrict__ WQ, const float* __restrict__ WK,
    float* __restrict__ Ppart)
{
    __shared__ float Xs[32][36];               // [mm][frow], pad 36 (bank spread)
    int bx = blockIdx.x;
    int mc = bx & 15, b = (bx >> 4) & 1, which = bx >> 5;
    int m0 = mc * 32;
    int t = threadIdx.x;                       // n = t

    const float* In = which ? Kin : Qin;
    const float* W  = which ? WK  : WQ;

    // stage X: 32 frows x 32 m  (frow = cc*8+cs -> srow)
#pragma unroll
    for (int i = 0; i < 2; ++i) {
        int idx = i * 512 + t;
        int fr = idx >> 5, mm = idx & 31;
        int cc = fr >> 3, cs = fr & 7;
        int srow = (cc < 2) ? (240 + 8 * cc + cs) : (8 * (cc - 2) + cs);
        Xs[mm][fr] = In[(b * 256 + srow) * 512 + m0 + mm];
    }
    __syncthreads();

    int h_i = t >> 6, g = t >> 7;
    int cc0 = (h_i & 1) * 2;                   // wave-uniform
    float acc[16];
#pragma unroll
    for (int j = 0; j < 16; ++j) acc[j] = 0.f;

    const float* wp = W + t;
#pragma unroll 4
    for (int mm = 0; mm < 32; ++mm) {
        float w = wp[(m0 + mm) * 512];         // block-wide coalesced 2KB
        const float4* xp = (const float4*)&Xs[mm][cc0 * 8];  // broadcast
        float4 x0 = xp[0], x1 = xp[1], x2 = xp[2], x3 = xp[3];
        acc[0]  += x0.x * w; acc[1]  += x0.y * w; acc[2]  += x0.z * w; acc[3]  += x0.w * w;
        acc[4]  += x1.x * w; acc[5]  += x1.y * w; acc[6]  += x1.z * w; acc[7]  += x1.w * w;
        acc[8]  += x2.x * w; acc[9]  += x2.y * w; acc[10] += x2.z * w; acc[11] += x2.w * w;
        acc[12] += x3.x * w; acc[13] += x3.y * w; acc[14] += x3.z * w; acc[15] += x3.w * w;
    }

    int d = t & 63;
    int base = ((which * 2 + b) * 4 + g) * 4;
#pragma unroll
    for (int j = 0; j < 16; ++j) {
        int ccj = cc0 + (j >> 3), cs = j & 7;
        Ppart[mc * 32768 + (base + ccj) * 512 + cs * 64 + d] = acc[j];
    }
}

// kB: F[f] = sum_{mc<16} Ppart[mc][f] + bias.  128 blocks x 256 thr.
__global__ void kB_proj_red(const float* __restrict__ Ppart,
                            const float* __restrict__ bQ, const float* __restrict__ bK,
                            float* __restrict__ F) {
    int f = blockIdx.x * 256 + threadIdx.x;
    float acc = 0.f;
#pragma unroll
    for (int kc = 0; kc < 16; ++kc) acc += Ppart[kc * 32768 + f];
    int which = f >> 14, cc = (f >> 9) & 3, g = (f >> 11) & 3, d = f & 63;
    int n = (g * 2 + (cc >> 1)) * 64 + d;
    F[f] = acc + (which ? bK[n] : bQ[n]);
}

// kC: Dt (8-lane dots + shfl) and SFK (pre-scaled x32).  48 blocks x 256 thr.
__global__ void kC_dtab_sfk(const float* __restrict__ F, float* __restrict__ Dt,
                            float* __restrict__ SFK) {
    int slot = blockIdx.x * 256 + threadIdx.x;
    if (slot < 8192) {
        int part = slot & 7, e = slot >> 3;
        int cs = e & 7, cc = (e >> 3) & 3, gk = (e >> 5) & 3,
            gq = (e >> 7) & 3, b = (e >> 9) & 1;
        const float* fq = F + ((b * 4 + gq) * 4 + cc) * 512 + cs * 64 + part * 8;
        const float* fk = F + (((2 + b) * 4 + gk) * 4 + cc) * 512 + cs * 64 + part * 8;
        float a = 0.f;
#pragma unroll
        for (int u = 0; u < 8; ++u) a += fq[u] * fk[u];
        a += __shfl_xor(a, 1);
        a += __shfl_xor(a, 2);
        a += __shfl_xor(a, 4);
        if (part == 0) Dt[e] = a * 0.125f;
    } else {
        int e = slot - 8192;
        int d = e & 63, c = (e >> 6) & 31, b = e >> 11;
        float a = 0.f;
#pragma unroll
        for (int gv = 0; gv < 4; ++gv)
            a += F[(((2 + b) * 4 + gv) * 4 + (c >> 3)) * 512 + (c & 7) * 64 + d];
        SFK[e] = 32.f * a;
    }
}

// kAttn: 1024 blocks x 256 thr.  Wave per (h,q); 2 lanes per k, 16 c each.
__global__ void kAttn(const float* __restrict__ Dt, const void* __restrict__ maskp,
                      const float* __restrict__ SFK, float* __restrict__ ctx,
                      float* __restrict__ attnp, int fill) {
    __shared__ float aws[4][32];
    int vb = blockIdx.x, t = threadIdx.x;
    if (fill) ((float4*)attnp)[vb * 256 + t] = make_float4(1.f, 1.f, 1.f, 1.f);
    int qb = vb & 63, h = (vb >> 6) & 7, b = vb >> 9;
    int wave = t >> 6, l = t & 63;
    int q = qb * 4 + wave;
    int half = l & 1, klo = l >> 1;
    int g_q = q & 3;
    int i_q = h * 32 + (q >> 3);
    bool up_q = (q & 4) == 0;
    int ak = klo & 3;
    bool up_k = (klo & 4) == 0;

    bool mbytes = sniff_mask_bytes((const unsigned int*)maskp);

    float sq[16];
    const float* Db = Dt + ((b * 4 + g_q) * 4 + ak) * 32 + half * 16;
#pragma unroll
    for (int j = 0; j < 16; ++j) {
        int cc = half * 2 + (j >> 3);
        int row = g_q * 64 + 30 + cc;
        bool vq = up_q ? (i_q >= 256 - row) : (i_q <= 255 - row);
        sq[j] = vq ? Db[j] : 0.f;
    }

    float A[16];
#pragma unroll
    for (int j = 0; j < 16; ++j) A[j] = 0.f;

    int qrow = (b * 256 + q) * 256;
    for (int r = 0; r < 8; ++r) {
        int k = r * 32 + klo;
        bool masked = mbytes ? (((const unsigned char*)maskp)[qrow + k] != 0)
                             : (((const int*)maskp)[qrow + k] != 0);
        if (masked) {
#pragma unroll
            for (int j = 0; j < 16; ++j) A[j] += 0.03125f;
            continue;
        }
        int i_k = h * 32 + (k >> 3);
        float s[16];
        float mx = -1e30f;
#pragma unroll
        for (int j = 0; j < 16; ++j) {
            int cc = half * 2 + (j >> 3);
            int row = ak * 64 + 30 + cc;
            bool vk = up_k ? (i_k >= 256 - row) : (i_k <= 255 - row);
            s[j] = vk ? sq[j] : 0.f;
            mx = fmaxf(mx, s[j]);
        }
        mx = fmaxf(mx, __shfl_xor(mx, 1));
        float den = 0.f;
#pragma unroll
        for (int j = 0; j < 16; ++j) { s[j] = __expf(s[j] - mx); den += s[j]; }
        den += __shfl_xor(den, 1);
        float inv = 1.f / den;
#pragma unroll
        for (int j = 0; j < 16; ++j) A[j] += s[j] * inv;
    }

#pragma unroll
    for (int off = 2; off < 64; off <<= 1) {
#pragma unroll
        for (int j = 0; j < 16; ++j) A[j] += __shfl_xor(A[j], off);
    }

    float* aw = aws[wave];
    if (l < 2) {
#pragma unroll
        for (int j = 0; j < 16; ++j) aw[l * 16 + j] = A[j];
    }
    float acc = 0.f;
    const float* S = SFK + b * 2048;
#pragma unroll
    for (int c = 0; c < 32; ++c) acc += aw[c] * S[c * 64 + l];
    ctx[(b * 256 + q) * 512 + h * 64 + l] = acc;
}

// kG4LN: outer-product Wo GEMM + bias + residual + LayerNorm, fused.
// 128 blocks x 512 thr; block = 4 output rows.  (r9 version, ~8.8us warm.)
__global__ __launch_bounds__(512) void kG4LN(
    const float* __restrict__ ctx, const float* __restrict__ Wo,
    const float* __restrict__ bo, const float* __restrict__ Qin,
    const float* __restrict__ gamma, const float* __restrict__ beta,
    float* __restrict__ out)
{
    __shared__ float  Cl[4][512];
    __shared__ float4 red4[8][4][64];
    __shared__ float  red2[8][2];

    int t = threadIdx.x, r0 = blockIdx.x * 4;
    int w = t >> 6, l = t & 63;

    ((float4*)Cl)[t] = ((const float4*)&ctx[r0 * 512])[t];
    __syncthreads();

    const float4* WoV = (const float4*)Wo;
    const float4* pA = WoV + (size_t)(w * 64) * 128 + l;
    const float4* pB = pA + 64;
    float4 a0A = {0,0,0,0}, a1A = {0,0,0,0}, a2A = {0,0,0,0}, a3A = {0,0,0,0};
    float4 a0B = {0,0,0,0}, a1B = {0,0,0,0}, a2B = {0,0,0,0}, a3B = {0,0,0,0};
    int m0 = w * 64;
    float4 wA = pA[0], wB = pB[0];
#pragma unroll 4
    for (int mm = 0; mm < 63; ++mm) {
        float4 nA = pA[(mm + 1) * 128];
        float4 nB = pB[(mm + 1) * 128];
        float s0 = Cl[0][m0 + mm], s1 = Cl[1][m0 + mm];
        float s2 = Cl[2][m0 + mm], s3 = Cl[3][m0 + mm];
        FMA4(a0A, s0, wA); FMA4(a1A, s1, wA); FMA4(a2A, s2, wA); FMA4(a3A, s3, wA);
        FMA4(a0B, s0, wB); FMA4(a1B, s1, wB); FMA4(a2B, s2, wB); FMA4(a3B, s3, wB);
        wA = nA; wB = nB;
    }
    {
        float s0 = Cl[0][m0 + 63], s1 = Cl[1][m0 + 63];
        float s2 = Cl[2][m0 + 63], s3 = Cl[3][m0 + 63];
        FMA4(a0A, s0, wA); FMA4(a1A, s1, wA); FMA4(a2A, s2, wA); FMA4(a3A, s3, wA);
        FMA4(a0B, s0, wB); FMA4(a1B, s1, wB); FMA4(a2B, s2, wB); FMA4(a3B, s3, wB);
    }

    red4[w][0][l] = a0A; red4[w][1][l] = a1A; red4[w][2][l] = a2A; red4[w][3][l] = a3A;
    __syncthreads();
    if (t < 256) {
        int r = t >> 6, c4 = t & 63;
        float4 s = red4[0][r][c4];
#pragma unroll
        for (int w2 = 1; w2 < 8; ++w2) {
            float4 v = red4[w2][r][c4];
            s.x += v.x; s.y += v.y; s.z += v.z; s.w += v.w;
        }
        float4 bb = ((const float4*)bo)[c4];
        float4 qq = ((const float4*)Qin)[(r0 + r) * 128 + c4];
        s.x += bb.x + qq.x; s.y += bb.y + qq.y;
        s.z += bb.z + qq.z; s.w += bb.w + qq.w;
        *(float4*)&Cl[r][c4 * 4] = s;
    }
    __syncthreads();
    red4[w][0][l] = a0B; red4[w][1][l] = a1B; red4[w][2][l] = a2B; red4[w][3][l] = a3B;
    __syncthreads();
    if (t < 256) {
        int r = t >> 6, c4 = t & 63;
        float4 s = red4[0][r][c4];
#pragma unroll
        for (int w2 = 1; w2 < 8; ++w2) {
            float4 v = red4[w2][r][c4];
            s.x += v.x; s.y += v.y; s.z += v.z; s.w += v.w;
        }
        float4 bb = ((const float4*)bo)[64 + c4];
        float4 qq = ((const float4*)Qin)[(r0 + r) * 128 + 64 + c4];
        s.x += bb.x + qq.x; s.y += bb.y + qq.y;
        s.z += bb.z + qq.z; s.w += bb.w + qq.w;
        *(float4*)&Cl[r][256 + c4 * 4] = s;
    }
    __syncthreads();

    int r = t >> 7, c = t & 127;
    float v0 = Cl[r][c], v1 = Cl[r][c + 128], v2 = Cl[r][c + 256], v3 = Cl[r][c + 384];
    float s1 = v0 + v1 + v2 + v3;
    float s2 = v0 * v0 + v1 * v1 + v2 * v2 + v3 * v3;
#pragma unroll
    for (int off = 1; off < 64; off <<= 1) {
        s1 += __shfl_xor(s1, off);
        s2 += __shfl_xor(s2, off);
    }
    if (l == 0) { red2[w][0] = s1; red2[w][1] = s2; }
    __syncthreads();
    float tot1 = red2[2 * r][0] + red2[2 * r + 1][0];
    float tot2 = red2[2 * r][1] + red2[2 * r + 1][1];
    float mu = tot1 * (1.f / 512.f);
    float var = tot2 * (1.f / 512.f) - mu * mu;
    float rs = rsqrtf(var + LN_EPS);
    float* op = out + (r0 + r) * 512;
    op[c]       = (v0 - mu) * rs * gamma[c]       + beta[c];
    op[c + 128] = (v1 - mu) * rs * gamma[c + 128] + beta[c + 128];
    op[c + 256] = (v2 - mu) * rs * gamma[c + 256] + beta[c + 256];
    op[c + 384] = (v3 - mu) * rs * gamma[c + 384] + beta[c + 384];
}

// plan-B only: restore attn_out region (which hosted scratch) to 1.0
__global__ void k5_fill(float* __restrict__ p, int n) {
    int i = (blockIdx.x * 256 + threadIdx.x) * 4;
    float4 one = make_float4(1.f, 1.f, 1.f, 1.f);
    for (; i < n; i += gridDim.x * 256 * 4) *(float4*)(p + i) = one;
}

extern "C" void kernel_launch(void* const* d_in, const int* in_sizes, int n_in,
                              void* d_out, int out_size, void* d_ws, size_t ws_size,
                              hipStream_t stream) {
    (void)in_sizes; (void)n_in; (void)out_size;
    const float* Qin  = (const float*)d_in[0];
    const float* Kin  = (const float*)d_in[1];
    const void*  mask = d_in[3];
    const float* WQ   = (const float*)d_in[4];
    const float* bQ   = (const float*)d_in[5];
    const float* WK   = (const float*)d_in[6];
    const float* bK   = (const float*)d_in[7];
    const float* Wo   = (const float*)d_in[10];
    const float* bo   = (const float*)d_in[11];
    const float* gamma= (const float*)d_in[12];
    const float* beta = (const float*)d_in[13];

    float* out   = (float*)d_out;
    float* attnp = out + 262144;                  // 1,048,576 floats (output 1)

    const size_t NEED = 824320ull * sizeof(float);
    if (ws_size >= NEED) {
        // Plan A: scratch in d_ws.
        float* ws    = (float*)d_ws;
        float* Ppart = ws;                        // 524288 (16 x 32768)
        float* F     = ws + 524288;               // 32768
        float* Dt    = ws + 557056;               // 1024
        float* SFK   = ws + 558080;               // 4096
        float* ctx   = ws + 562176;               // 262144

        kAo_proj_part<<<dim3(64),  dim3(512), 0, stream>>>(Qin, Kin, WQ, WK, Ppart);
        kB_proj_red <<<dim3(128),  dim3(256), 0, stream>>>(Ppart, bQ, bK, F);
        kC_dtab_sfk <<<dim3(48),   dim3(256), 0, stream>>>(F, Dt, SFK);
        kAttn       <<<dim3(1024), dim3(256), 0, stream>>>(Dt, mask, SFK, ctx, attnp, 1);
        kG4LN       <<<dim3(128),  dim3(512), 0, stream>>>(ctx, Wo, bo, Qin, gamma, beta, out);
    } else {
        // Plan B: scratch in attn_out region; restore with fill at end.
        float* Ppart = attnp;                     // [0, 524288)
        float* F     = attnp + 524288;            // [524288, 557056)
        float* Dt    = attnp + 557056;            // [557056, 558080)
        float* SFK   = attnp + 558080;            // [558080, 562176)
        float* ctx   = attnp + 786432;            // [786432, 1048576)

        kAo_proj_part<<<dim3(64),  dim3(512), 0, stream>>>(Qin, Kin, WQ, WK, Ppart);
        kB_proj_red <<<dim3(128),  dim3(256), 0, stream>>>(Ppart, bQ, bK, F);
        kC_dtab_sfk <<<dim3(48),   dim3(256), 0, stream>>>(F, Dt, SFK);
        kAttn       <<<dim3(1024), dim3(256), 0, stream>>>(Dt, mask, SFK, ctx, attnp, 0);
        kG4LN       <<<dim3(128),  dim3(512), 0, stream>>>(ctx, Wo, bo, Qin, gamma, beta, out);
        k5_fill     <<<dim3(256),  dim3(256), 0, stream>>>(attnp, 1048576);
    }
}